// Round 4
// baseline (169.096 us; speedup 1.0000x reference)
//
#include <hip/hip_runtime.h>

#define B_  32
#define T_  4096
#define D_  256
#define D4_ 64          // D_/4 float4 columns
#define LCH 128         // timesteps per chunk (block)
#define LW  32          // timesteps per wave
#define NCH (T_/LCH)    // 32 chunks per row
#define NTASK (B_*NCH)  // 1024 chunk-tasks

typedef float f32x4 __attribute__((ext_vector_type(4)));

__device__ __forceinline__ f32x4 sigmoid4(f32x4 v) {
    f32x4 r;
    r[0] = 1.0f / (1.0f + expf(-v[0]));
    r[1] = 1.0f / (1.0f + expf(-v[1]));
    r[2] = 1.0f / (1.0f + expf(-v[2]));
    r[3] = 1.0f / (1.0f + expf(-v[3]));
    return r;
}

// ---------------- single-pass fused kernel (decoupled lookback) -------------

__global__ void ema_init(int* __restrict__ flags, int* __restrict__ ticket) {
    int i = blockIdx.x * blockDim.x + threadIdx.x;
    if (i < NTASK) flags[i] = 0;
    if (i == 0) *ticket = 0;
}

__global__ __launch_bounds__(256) void ema_fused(
    const f32x4* __restrict__ x, const f32x4* __restrict__ la,
    f32x4* __restrict__ y, f32x4* __restrict__ A, f32x4* __restrict__ P,
    int* __restrict__ flags, int* __restrict__ ticket)
{
    __shared__ int s_vid;
    __shared__ f32x4 s_E[4][64];
    __shared__ f32x4 s_H[64];

    if (threadIdx.x == 0) s_vid = atomicAdd(ticket, 1);
    __syncthreads();
    const int vid  = s_vid;
    const int b    = vid % B_;      // predecessor (b,c-1) has ticket vid-B_
    const int c    = vid / B_;
    const int w    = threadIdx.x >> 6;
    const int lane = threadIdx.x & 63;

    const f32x4 al = sigmoid4(la[lane]);
    const f32x4 om = 1.0f - al;
    f32x4 a32 = al;                        // al^32
    #pragma unroll
    for (int k = 0; k < 5; ++k) a32 = a32 * a32;

    // local zero-init scan over this wave's 32 timesteps, outputs in regs
    const size_t base = ((size_t)b * T_ + (size_t)c * LCH + (size_t)w * LW) * D4_ + lane;
    f32x4 yl[LW];
    f32x4 s = 0.0f;
    const bool first_global = (c == 0 && w == 0);
    #pragma unroll
    for (int t = 0; t < LW; ++t) {
        f32x4 xv = __builtin_nontemporal_load(&x[base + (size_t)t * D4_]);
        f32x4 bv = om * xv;
        if (t == 0 && first_global) bv = xv;   // y_0 = x_0 exactly
        s = al * s + bv;
        yl[t] = s;
    }
    s_E[w][lane] = s;
    __syncthreads();

    // intra-block exclusive prefix over wave sub-chunks (zero-init)
    f32x4 Sw = 0.0f;
    #pragma unroll
    for (int j = 0; j < 3; ++j)
        if (j < w) Sw = a32 * Sw + s_E[j][lane];

    // wave 3 runs the global decoupled-lookback protocol
    if (w == 3) {
        f32x4 Ec = a32 * Sw + s;            // full-chunk aggregate
        f32x4 aL = a32 * a32; aL = aL * aL; // al^128
        f32x4 H = 0.0f;
        if (c > 0) {
            A[(size_t)vid * 64 + lane] = Ec;
            __hip_atomic_store(&flags[vid], 1, __ATOMIC_RELEASE, __HIP_MEMORY_SCOPE_AGENT);
            f32x4 coef = 1.0f;
            int j = vid - B_;
            while (true) {
                int f = 0;
                if (lane == 0)
                    f = __hip_atomic_load(&flags[j], __ATOMIC_ACQUIRE, __HIP_MEMORY_SCOPE_AGENT);
                f = __shfl(f, 0, 64);
                if (f == 0) { __builtin_amdgcn_s_sleep(4); continue; }
                if (f == 2) { H += coef * P[(size_t)j * 64 + lane]; break; }
                H += coef * A[(size_t)j * 64 + lane];
                coef = coef * aL;
                j -= B_;
            }
        }
        f32x4 Pc = aL * H + Ec;             // inclusive prefix after chunk c
        P[(size_t)vid * 64 + lane] = Pc;
        __hip_atomic_store(&flags[vid], 2, __ATOMIC_RELEASE, __HIP_MEMORY_SCOPE_AGENT);
        s_H[lane] = H;
    }
    __syncthreads();
    const f32x4 H = s_H[lane];

    // state before this wave = a32^w * H + Sw ; then y_t = yl[t] + al^{t+1}*Sb
    f32x4 pw = 1.0f;
    #pragma unroll
    for (int j = 0; j < 3; ++j)
        if (j < w) pw = pw * a32;
    const f32x4 Sb = pw * H + Sw;

    f32x4 coef = al;
    #pragma unroll
    for (int t = 0; t < LW; ++t) {
        f32x4 out = yl[t] + coef * Sb;
        __builtin_nontemporal_store(out, &y[base + (size_t)t * D4_]);
        coef = coef * al;
    }
}

// ---------------- 3-pass fallback (only if ws_size is tiny) -----------------

__global__ __launch_bounds__(256) void ema_carry(
    const f32x4* __restrict__ x, const f32x4* __restrict__ la,
    f32x4* __restrict__ E, int NC, int L) {
    const int wid  = threadIdx.x >> 6;
    const int lane = threadIdx.x & 63;
    const int g = blockIdx.x * 4 + wid;
    const int b = g / NC;
    const int c = g % NC;
    const f32x4 al = sigmoid4(la[lane]);
    const f32x4 om = 1.0f - al;
    size_t idx = ((size_t)b * T_ + (size_t)c * L) * D4_ + lane;
    f32x4 yv = 0.0f;
    int i0 = 0;
    if (c == 0) { yv = x[idx]; idx += D4_; i0 = 1; }
    for (int i = i0; i < L; ++i) {
        f32x4 xv = x[idx]; idx += D4_;
        yv = al * yv + om * xv;
    }
    E[(size_t)g * D4_ + lane] = yv;
}

__global__ __launch_bounds__(64) void ema_combine(
    const f32x4* __restrict__ la, f32x4* __restrict__ E, int NC, int log2L) {
    const int b = blockIdx.x;
    const int lane = threadIdx.x;
    const f32x4 al = sigmoid4(la[lane]);
    f32x4 p = al;
    for (int k = 0; k < log2L; ++k) p = p * p;
    f32x4 s = 0.0f;
    for (int c = 0; c < NC; ++c) {
        size_t o = ((size_t)b * NC + c) * D4_ + lane;
        f32x4 e = E[o];
        E[o] = s;
        s = p * s + e;
    }
}

__global__ __launch_bounds__(256) void ema_apply(
    const f32x4* __restrict__ x, const f32x4* __restrict__ la,
    const f32x4* __restrict__ H, f32x4* __restrict__ yout, int NC, int L) {
    const int wid  = threadIdx.x >> 6;
    const int lane = threadIdx.x & 63;
    const int g = blockIdx.x * 4 + wid;
    const int b = g / NC;
    const int c = g % NC;
    const f32x4 al = sigmoid4(la[lane]);
    const f32x4 om = 1.0f - al;
    size_t idx = ((size_t)b * T_ + (size_t)c * L) * D4_ + lane;
    f32x4 acc;
    int i0 = 0;
    if (c == 0) {
        acc = x[idx];
        __builtin_nontemporal_store(acc, &yout[idx]);
        idx += D4_; i0 = 1;
    } else {
        acc = H[(size_t)g * D4_ + lane];
    }
    for (int i = i0; i < L; ++i) {
        f32x4 xv = x[idx];
        acc = al * acc + om * xv;
        __builtin_nontemporal_store(acc, &yout[idx]);
        idx += D4_;
    }
}

// ---------------------------------------------------------------------------

extern "C" void kernel_launch(void* const* d_in, const int* in_sizes, int n_in,
                              void* d_out, int out_size, void* d_ws, size_t ws_size,
                              hipStream_t stream) {
    const f32x4* x  = (const f32x4*)d_in[0];
    const f32x4* la = (const f32x4*)d_in[1];
    f32x4* out = (f32x4*)d_out;

    const size_t offA = 0;
    const size_t offP = offA + (size_t)NTASK * 64 * sizeof(f32x4);   // 1 MiB
    const size_t offF = offP + (size_t)NTASK * 64 * sizeof(f32x4);   // 2 MiB
    const size_t offT = offF + (size_t)NTASK * sizeof(int);
    const size_t need = offT + sizeof(int);

    if (ws_size >= need) {
        f32x4* A = (f32x4*)((char*)d_ws + offA);
        f32x4* P = (f32x4*)((char*)d_ws + offP);
        int* flags  = (int*)((char*)d_ws + offF);
        int* ticket = (int*)((char*)d_ws + offT);
        ema_init <<<(NTASK + 255) / 256, 256, 0, stream>>>(flags, ticket);
        ema_fused<<<NTASK, 256, 0, stream>>>(x, la, out, A, P, flags, ticket);
    } else {
        int NC = 128;
        while (NC > 1 && (size_t)B_ * NC * D_ * sizeof(float) > ws_size) NC >>= 1;
        const int L = T_ / NC;
        int log2L = 0;
        while ((1 << log2L) < L) ++log2L;
        f32x4* E = (f32x4*)d_ws;
        const int ntasks = B_ * NC;
        ema_carry  <<<ntasks / 4, 256, 0, stream>>>(x, la, E, NC, L);
        ema_combine<<<B_, 64, 0, stream>>>(la, E, NC, log2L);
        ema_apply  <<<ntasks / 4, 256, 0, stream>>>(x, la, E, out, NC, L);
    }
}

// Round 5
// 71.987 us; speedup vs baseline: 2.3490x; 2.3490x over previous
//
#include <hip/hip_runtime.h>

#define B_  32
#define T_  4096
#define D_  256
#define D4_ 64          // D_/4 float4 columns

typedef float f32x4 __attribute__((ext_vector_type(4)));

__device__ __forceinline__ f32x4 sigmoid4(f32x4 v) {
    f32x4 r;
    r[0] = 1.0f / (1.0f + expf(-v[0]));
    r[1] = 1.0f / (1.0f + expf(-v[1]));
    r[2] = 1.0f / (1.0f + expf(-v[2]));
    r[3] = 1.0f / (1.0f + expf(-v[3]));
    return r;
}

// K1: per-chunk local scan with zero init (exact x0 for chunk 0),
// writes chunk-end aggregate E[b][c][d4]. One chunk per wave.
__global__ __launch_bounds__(256) void ema_carry(
    const f32x4* __restrict__ x, const f32x4* __restrict__ la,
    f32x4* __restrict__ E, int NC, int L) {
    const int wid  = threadIdx.x >> 6;
    const int lane = threadIdx.x & 63;
    const int g = blockIdx.x * 4 + wid;        // chunk-task id in [0, B_*NC)
    const int b = g / NC;
    const int c = g % NC;

    const f32x4 al = sigmoid4(la[lane]);
    const f32x4 om = 1.0f - al;

    size_t idx = ((size_t)b * T_ + (size_t)c * L) * D4_ + lane;
    f32x4 y = 0.0f;
    int i0 = 0;
    if (c == 0) {                               // y_0 = x_0 exactly
        y = x[idx];
        idx += D4_;
        i0 = 1;
    }
    #pragma unroll 8
    for (int i = i0; i < L; ++i) {
        y = al * y + om * x[idx];
        idx += D4_;
    }
    E[(size_t)g * D4_ + lane] = y;
}

// K2: per chunk, fold predecessor aggregates in-register (batched loads),
// then rescan the chunk from x (L3-hot) and write y with NT stores.
__global__ __launch_bounds__(256) void ema_apply(
    const f32x4* __restrict__ x, const f32x4* __restrict__ la,
    const f32x4* __restrict__ E, f32x4* __restrict__ yout,
    int NC, int L, int log2L) {
    const int wid  = threadIdx.x >> 6;
    const int lane = threadIdx.x & 63;
    const int g = blockIdx.x * 4 + wid;
    const int b = g / NC;
    const int c = g % NC;

    const f32x4 al = sigmoid4(la[lane]);
    const f32x4 om = 1.0f - al;

    f32x4 aL = al;                              // al^L via log2L squarings
    for (int k = 0; k < log2L; ++k) aL = aL * aL;
    const f32x4 aL2 = aL * aL;
    const f32x4 aL4 = aL2 * aL2;

    // H = incoming state for chunk c = sum_{j<c} aL^(c-1-j) * E[b][j]
    const f32x4* Eb = E + (size_t)b * NC * D4_;
    f32x4 H = 0.0f;
    int j = 0;
    for (; j + 4 <= c; j += 4) {                // batch 4 loads per L2 trip
        f32x4 e0 = Eb[(size_t)(j + 0) * D4_ + lane];
        f32x4 e1 = Eb[(size_t)(j + 1) * D4_ + lane];
        f32x4 e2 = Eb[(size_t)(j + 2) * D4_ + lane];
        f32x4 e3 = Eb[(size_t)(j + 3) * D4_ + lane];
        H = aL4 * H + (((e0 * aL + e1) * aL + e2) * aL + e3);
    }
    for (; j < c; ++j)
        H = aL * H + Eb[(size_t)j * D4_ + lane];

    // rescan chunk from incoming state H
    size_t idx = ((size_t)b * T_ + (size_t)c * L) * D4_ + lane;
    f32x4 acc = H;
    int i0 = 0;
    if (c == 0) {
        acc = x[idx];                           // y_0 = x_0
        __builtin_nontemporal_store(acc, &yout[idx]);
        idx += D4_;
        i0 = 1;
    }
    #pragma unroll 8
    for (int i = i0; i < L; ++i) {
        acc = al * acc + om * x[idx];
        __builtin_nontemporal_store(acc, &yout[idx]);
        idx += D4_;
    }
}

extern "C" void kernel_launch(void* const* d_in, const int* in_sizes, int n_in,
                              void* d_out, int out_size, void* d_ws, size_t ws_size,
                              hipStream_t stream) {
    const f32x4* x  = (const f32x4*)d_in[0];
    const f32x4* la = (const f32x4*)d_in[1];
    f32x4* out = (f32x4*)d_out;

    // NC chunks/row; E needs B_*NC*D_ floats in d_ws.
    int NC = 64;
    while (NC > 1 && (size_t)B_ * NC * D_ * sizeof(float) > ws_size) NC >>= 1;
    const int L = T_ / NC;
    int log2L = 0;
    while ((1 << log2L) < L) ++log2L;

    f32x4* E = (f32x4*)d_ws;
    const int ntasks = B_ * NC;                 // 4 chunk-tasks per block
    dim3 blk(256);
    dim3 grd(ntasks / 4);

    ema_carry<<<grd, blk, 0, stream>>>(x, la, E, NC, L);
    ema_apply<<<grd, blk, 0, stream>>>(x, la, E, out, NC, L, log2L);
}